// Round 1
// baseline (2290.409 us; speedup 1.0000x reference)
//
#include <hip/hip_runtime.h>
#include <math.h>

// ---------------- degree / norm precompute ----------------

__global__ void deg_init_kernel(float* deg, int n) {
    int i = blockIdx.x * blockDim.x + threadIdx.x;
    if (i < n) deg[i] = 1.0f;   // self-loop
}

__global__ void deg_count_kernel(const int* __restrict__ dst, float* deg, int e) {
    int i = blockIdx.x * blockDim.x + threadIdx.x;
    if (i < e) atomicAdd(&deg[dst[i]], 1.0f);
}

__global__ void dinv_kernel(float* deg, int n) {
    int i = blockIdx.x * blockDim.x + threadIdx.x;
    if (i < n) deg[i] = rsqrtf(deg[i]);
}

__global__ void norm_kernel(const int* __restrict__ src, const int* __restrict__ dst,
                            const float* __restrict__ dinv, float* __restrict__ nrm, int e) {
    int i = blockIdx.x * blockDim.x + threadIdx.x;
    if (i < e) nrm[i] = dinv[src[i]] * dinv[dst[i]];
}

// ---------------- fp32 tiled GEMM: C = act(A) @ W (+bias) ----------------
// BM=64, BN=64, BK=16, 256 threads, 4x4 micro-tile per thread.

template<bool RELU, bool BIAS>
__global__ __launch_bounds__(256) void gemm_kernel(
    const float* __restrict__ A, const float* __restrict__ W,
    const float* __restrict__ bias, float* __restrict__ C,
    int Nrows, int K, int M)
{
    const int BM = 64, BN = 64, BK = 16;
    __shared__ float As[BK][BM + 4];   // A stored transposed: As[k][row]
    __shared__ float Bs[BK][BN];

    const int tid = threadIdx.x;
    const int tx = tid & 15, ty = tid >> 4;
    const int row0 = blockIdx.y * BM;
    const int col0 = blockIdx.x * BN;

    const int ar  = tid >> 2;         // 0..63  (A tile row)
    const int ac4 = (tid & 3) * 4;    // 0,4,8,12 (A tile k-col, float4)
    const int br  = tid >> 4;         // 0..15  (B tile k-row)
    const int bc4 = (tid & 15) * 4;   // 0..60  (B tile col, float4)

    float acc[4][4] = {};

    for (int k0 = 0; k0 < K; k0 += BK) {
        float4 av = make_float4(0.f, 0.f, 0.f, 0.f);
        const int arow = row0 + ar;
        if (arow < Nrows) {
            av = *(const float4*)(A + (size_t)arow * K + k0 + ac4);
            if (RELU) {
                av.x = fmaxf(av.x, 0.f); av.y = fmaxf(av.y, 0.f);
                av.z = fmaxf(av.z, 0.f); av.w = fmaxf(av.w, 0.f);
            }
        }
        float4 bv = make_float4(0.f, 0.f, 0.f, 0.f);
        const int bcol = col0 + bc4;
        if (bcol + 3 < M) {
            bv = *(const float4*)(W + (size_t)(k0 + br) * M + bcol);
        }

        __syncthreads();   // previous iter's compute done before overwriting LDS
        As[ac4 + 0][ar] = av.x;
        As[ac4 + 1][ar] = av.y;
        As[ac4 + 2][ar] = av.z;
        As[ac4 + 3][ar] = av.w;
        *(float4*)&Bs[br][bc4] = bv;
        __syncthreads();

        #pragma unroll
        for (int kk = 0; kk < BK; ++kk) {
            float4 a = *(const float4*)&As[kk][ty * 4];
            float4 b = *(const float4*)&Bs[kk][tx * 4];
            float aa[4] = {a.x, a.y, a.z, a.w};
            float bb[4] = {b.x, b.y, b.z, b.w};
            #pragma unroll
            for (int i = 0; i < 4; ++i)
                #pragma unroll
                for (int j = 0; j < 4; ++j)
                    acc[i][j] = fmaf(aa[i], bb[j], acc[i][j]);
        }
    }

    #pragma unroll
    for (int i = 0; i < 4; ++i) {
        const int r = row0 + ty * 4 + i;
        if (r >= Nrows) continue;
        const int c = col0 + tx * 4;
        if (c + 3 < M) {
            float4 o;
            o.x = acc[i][0]; o.y = acc[i][1]; o.z = acc[i][2]; o.w = acc[i][3];
            if (BIAS) {
                o.x += bias[c + 0]; o.y += bias[c + 1];
                o.z += bias[c + 2]; o.w += bias[c + 3];
            }
            *(float4*)(C + (size_t)r * M + c) = o;
        } else {
            for (int j = 0; j < 4; ++j)
                if (c + j < M)
                    C[(size_t)r * M + c + j] = acc[i][j] + (BIAS ? bias[c + j] : 0.f);
        }
    }
}

// ---------------- aggregation: init with self-loop + bias ----------------
// out[n,f] = h[n,f] * dinv[n]^2 + bias[f]     (H == 256 hard-coded: 64 float4 groups)

__global__ void agg_init_kernel(const float* __restrict__ h, const float* __restrict__ dinv,
                                const float* __restrict__ bias, float* __restrict__ out, int n) {
    int idx = blockIdx.x * blockDim.x + threadIdx.x;
    int total = n * 64;
    if (idx >= total) return;
    int node = idx >> 6;
    int f = (idx & 63) * 4;
    float di = dinv[node];
    float w = di * di;
    float4 v = ((const float4*)h)[idx];
    float4 o;
    o.x = v.x * w + bias[f + 0];
    o.y = v.y * w + bias[f + 1];
    o.z = v.z * w + bias[f + 2];
    o.w = v.w * w + bias[f + 3];
    ((float4*)out)[idx] = o;
}

// ---------------- edge scatter: out[dst] += h[src] * norm ----------------
// 1 wave per edge, lane handles 4 features (H == 256).

__global__ __launch_bounds__(256) void scatter_kernel(
    const float* __restrict__ h, const float* __restrict__ nrm,
    const int* __restrict__ src, const int* __restrict__ dst,
    float* __restrict__ out, int e)
{
    int eid = blockIdx.x * 4 + (threadIdx.x >> 6);
    if (eid >= e) return;
    int lane = threadIdx.x & 63;
    int s = src[eid], d = dst[eid];
    float w = nrm[eid];
    const float4 v = *(const float4*)(h + (size_t)s * 256 + lane * 4);
    float* o = out + (size_t)d * 256 + lane * 4;
    atomicAdd(o + 0, v.x * w);
    atomicAdd(o + 1, v.y * w);
    atomicAdd(o + 2, v.z * w);
    atomicAdd(o + 3, v.w * w);
}

// ---------------- launch ----------------

extern "C" void kernel_launch(void* const* d_in, const int* in_sizes, int n_in,
                              void* d_out, int out_size, void* d_ws, size_t ws_size,
                              hipStream_t stream) {
    const float* x  = (const float*)d_in[0];
    const int*   ei = (const int*)d_in[1];
    const float* W1 = (const float*)d_in[2];
    const float* b1 = (const float*)d_in[3];
    const float* W2 = (const float*)d_in[4];
    const float* b2 = (const float*)d_in[5];
    const float* Wc = (const float*)d_in[6];
    const float* bc = (const float*)d_in[7];
    float* out = (float*)d_out;

    const int E = in_sizes[1] / 2;
    const int N = in_sizes[0] / 128;
    const int F_IN = 128, H = 256, C = 32;
    const int* src = ei;
    const int* dst = ei + E;

    float* ws   = (float*)d_ws;
    float* bufA = ws;                          // N*H  (GEMM output h)
    float* bufB = bufA + (size_t)N * H;        // N*H  (aggregated)
    float* dinv = bufB + (size_t)N * H;        // N
    float* nrm  = dinv + N;                    // E

    const int TB = 256;
    deg_init_kernel <<<(N + TB - 1) / TB, TB, 0, stream>>>(dinv, N);
    deg_count_kernel<<<(E + TB - 1) / TB, TB, 0, stream>>>(dst, dinv, E);
    dinv_kernel     <<<(N + TB - 1) / TB, TB, 0, stream>>>(dinv, N);
    norm_kernel     <<<(E + TB - 1) / TB, TB, 0, stream>>>(src, dst, dinv, nrm, E);

    dim3 g1((H + 63) / 64, (N + 63) / 64);
    // layer 1: h1 = x @ W1
    gemm_kernel<false, false><<<g1, 256, 0, stream>>>(x, W1, nullptr, bufA, N, F_IN, H);
    agg_init_kernel<<<((size_t)N * 64 + TB - 1) / TB, TB, 0, stream>>>(bufA, dinv, b1, bufB, N);
    scatter_kernel <<<(E + 3) / 4, 256, 0, stream>>>(bufA, nrm, src, dst, bufB, E);

    // layer 2: h2 = relu(agg1) @ W2
    gemm_kernel<true, false><<<g1, 256, 0, stream>>>(bufB, W2, nullptr, bufA, N, H, H);
    agg_init_kernel<<<((size_t)N * 64 + TB - 1) / TB, TB, 0, stream>>>(bufA, dinv, b2, bufB, N);
    scatter_kernel <<<(E + 3) / 4, 256, 0, stream>>>(bufA, nrm, src, dst, bufB, E);

    // classifier: out = relu(agg2) @ Wc + bc
    dim3 g3((C + 63) / 64, (N + 63) / 64);
    gemm_kernel<true, true><<<g3, 256, 0, stream>>>(bufB, Wc, bc, out, N, H, C);
}

// Round 2
// 500.986 us; speedup vs baseline: 4.5718x; 4.5718x over previous
//
#include <hip/hip_runtime.h>
#include <math.h>

// ---------------- CSR build ----------------

__global__ void zero_int_kernel(int* p, int n) {
    int i = blockIdx.x * blockDim.x + threadIdx.x;
    if (i < n) p[i] = 0;
}

__global__ void deg_count_kernel(const int* __restrict__ dst, int* deg, int e) {
    int i = blockIdx.x * blockDim.x + threadIdx.x;
    if (i < e) atomicAdd(&deg[dst[i]], 1);
}

__global__ void dinv_kernel(const int* __restrict__ deg, float* dinv, int n) {
    int i = blockIdx.x * blockDim.x + threadIdx.x;
    if (i < n) dinv[i] = rsqrtf((float)deg[i] + 1.0f);   // +1 self-loop
}

// single-block exclusive scan: off[0]=0, off[i+1]=sum(deg[0..i])
__global__ __launch_bounds__(1024) void scan_kernel(const int* __restrict__ deg,
                                                    int* __restrict__ off, int n) {
    __shared__ int sdata[1024];
    __shared__ int carry_s;
    if (threadIdx.x == 0) { carry_s = 0; off[0] = 0; }
    __syncthreads();
    for (int base = 0; base < n; base += 1024) {
        int i = base + threadIdx.x;
        int v = (i < n) ? deg[i] : 0;
        sdata[threadIdx.x] = v;
        __syncthreads();
        for (int s = 1; s < 1024; s <<= 1) {
            int t = (threadIdx.x >= s) ? sdata[threadIdx.x - s] : 0;
            __syncthreads();
            sdata[threadIdx.x] += t;
            __syncthreads();
        }
        if (i < n) off[i + 1] = carry_s + sdata[threadIdx.x];
        __syncthreads();
        if (threadIdx.x == 1023) carry_s += sdata[1023];
        __syncthreads();
    }
}

__global__ void copy_int_kernel(const int* __restrict__ a, int* __restrict__ b, int n) {
    int i = blockIdx.x * blockDim.x + threadIdx.x;
    if (i < n) b[i] = a[i];
}

__global__ void fill_kernel(const int* __restrict__ src, const int* __restrict__ dst,
                            const float* __restrict__ dinv, int* __restrict__ cursor,
                            int* __restrict__ esrc, float* __restrict__ enrm, int e) {
    int i = blockIdx.x * blockDim.x + threadIdx.x;
    if (i < e) {
        int d = dst[i], s = src[i];
        int pos = atomicAdd(&cursor[d], 1);
        esrc[pos] = s;
        enrm[pos] = dinv[s] * dinv[d];
    }
}

// ---------------- fp32 tiled GEMM: C = act(A) @ W (+bias) ----------------
// BM=64, BN=64, BK=16, 256 threads, 4x4 micro-tile per thread.

template<bool RELU, bool BIAS>
__global__ __launch_bounds__(256) void gemm_kernel(
    const float* __restrict__ A, const float* __restrict__ W,
    const float* __restrict__ bias, float* __restrict__ C,
    int Nrows, int K, int M)
{
    const int BM = 64, BN = 64, BK = 16;
    __shared__ float As[BK][BM + 4];   // A stored transposed: As[k][row]
    __shared__ float Bs[BK][BN];

    const int tid = threadIdx.x;
    const int tx = tid & 15, ty = tid >> 4;
    const int row0 = blockIdx.y * BM;
    const int col0 = blockIdx.x * BN;

    const int ar  = tid >> 2;
    const int ac4 = (tid & 3) * 4;
    const int br  = tid >> 4;
    const int bc4 = (tid & 15) * 4;

    float acc[4][4] = {};

    for (int k0 = 0; k0 < K; k0 += BK) {
        float4 av = make_float4(0.f, 0.f, 0.f, 0.f);
        const int arow = row0 + ar;
        if (arow < Nrows) {
            av = *(const float4*)(A + (size_t)arow * K + k0 + ac4);
            if (RELU) {
                av.x = fmaxf(av.x, 0.f); av.y = fmaxf(av.y, 0.f);
                av.z = fmaxf(av.z, 0.f); av.w = fmaxf(av.w, 0.f);
            }
        }
        float4 bv = make_float4(0.f, 0.f, 0.f, 0.f);
        const int bcol = col0 + bc4;
        if (bcol + 3 < M) {
            bv = *(const float4*)(W + (size_t)(k0 + br) * M + bcol);
        }

        __syncthreads();
        As[ac4 + 0][ar] = av.x;
        As[ac4 + 1][ar] = av.y;
        As[ac4 + 2][ar] = av.z;
        As[ac4 + 3][ar] = av.w;
        *(float4*)&Bs[br][bc4] = bv;
        __syncthreads();

        #pragma unroll
        for (int kk = 0; kk < BK; ++kk) {
            float4 a = *(const float4*)&As[kk][ty * 4];
            float4 b = *(const float4*)&Bs[kk][tx * 4];
            float aa[4] = {a.x, a.y, a.z, a.w};
            float bb[4] = {b.x, b.y, b.z, b.w};
            #pragma unroll
            for (int i = 0; i < 4; ++i)
                #pragma unroll
                for (int j = 0; j < 4; ++j)
                    acc[i][j] = fmaf(aa[i], bb[j], acc[i][j]);
        }
    }

    #pragma unroll
    for (int i = 0; i < 4; ++i) {
        const int r = row0 + ty * 4 + i;
        if (r >= Nrows) continue;
        const int c = col0 + tx * 4;
        if (c + 3 < M) {
            float4 o;
            o.x = acc[i][0]; o.y = acc[i][1]; o.z = acc[i][2]; o.w = acc[i][3];
            if (BIAS) {
                o.x += bias[c + 0]; o.y += bias[c + 1];
                o.z += bias[c + 2]; o.w += bias[c + 3];
            }
            *(float4*)(C + (size_t)r * M + c) = o;
        } else {
            for (int j = 0; j < 4; ++j)
                if (c + j < M)
                    C[(size_t)r * M + c + j] = acc[i][j] + (BIAS ? bias[c + j] : 0.f);
        }
    }
}

// ---------------- CSR gather: out[n] = h[n]*dinv[n]^2 + bias + sum_e h[src]*nrm ----------------
// one wave per node, lane holds 4 of 256 features.

__global__ __launch_bounds__(256) void gather_kernel(
    const float* __restrict__ h, const float* __restrict__ dinv,
    const float* __restrict__ bias, const int* __restrict__ off,
    const int* __restrict__ esrc, const float* __restrict__ enrm,
    float* __restrict__ out, int n)
{
    int node = blockIdx.x * 4 + (threadIdx.x >> 6);
    if (node >= n) return;
    int lane = threadIdx.x & 63;
    int f = lane * 4;

    float di = dinv[node];
    float w = di * di;
    float4 hv = *(const float4*)(h + (size_t)node * 256 + f);
    float4 acc;
    acc.x = hv.x * w + bias[f + 0];
    acc.y = hv.y * w + bias[f + 1];
    acc.z = hv.z * w + bias[f + 2];
    acc.w = hv.w * w + bias[f + 3];

    int e0 = off[node], e1 = off[node + 1];
    for (int e = e0; e < e1; ++e) {
        int s = esrc[e];
        float wn = enrm[e];
        float4 v = *(const float4*)(h + (size_t)s * 256 + f);
        acc.x = fmaf(v.x, wn, acc.x);
        acc.y = fmaf(v.y, wn, acc.y);
        acc.z = fmaf(v.z, wn, acc.z);
        acc.w = fmaf(v.w, wn, acc.w);
    }
    *(float4*)(out + (size_t)node * 256 + f) = acc;
}

// ---------------- launch ----------------

extern "C" void kernel_launch(void* const* d_in, const int* in_sizes, int n_in,
                              void* d_out, int out_size, void* d_ws, size_t ws_size,
                              hipStream_t stream) {
    const float* x  = (const float*)d_in[0];
    const int*   ei = (const int*)d_in[1];
    const float* W1 = (const float*)d_in[2];
    const float* b1 = (const float*)d_in[3];
    const float* W2 = (const float*)d_in[4];
    const float* b2 = (const float*)d_in[5];
    const float* Wc = (const float*)d_in[6];
    const float* bc = (const float*)d_in[7];
    float* out = (float*)d_out;

    const int E = in_sizes[1] / 2;
    const int N = in_sizes[0] / 128;
    const int F_IN = 128, H = 256, C = 32;
    const int* src = ei;
    const int* dst = ei + E;

    // workspace layout
    float* ws   = (float*)d_ws;
    float* bufA = ws;                               // N*H
    float* bufB = bufA + (size_t)N * H;             // N*H
    float* dinv = bufB + (size_t)N * H;             // N
    float* enrm = dinv + N;                         // E
    int*   deg  = (int*)(enrm + E);                 // N
    int*   off  = deg + N;                          // N+1
    int*   cur  = off + N + 1;                      // N
    int*   esrc = cur + N;                          // E

    const int TB = 256;
    // CSR build
    zero_int_kernel <<<(N + TB - 1) / TB, TB, 0, stream>>>(deg, N);
    deg_count_kernel<<<(E + TB - 1) / TB, TB, 0, stream>>>(dst, deg, E);
    dinv_kernel     <<<(N + TB - 1) / TB, TB, 0, stream>>>(deg, dinv, N);
    scan_kernel     <<<1, 1024, 0, stream>>>(deg, off, N);
    copy_int_kernel <<<(N + TB - 1) / TB, TB, 0, stream>>>(off, cur, N);
    fill_kernel     <<<(E + TB - 1) / TB, TB, 0, stream>>>(src, dst, dinv, cur, esrc, enrm, E);

    dim3 g1((H + 63) / 64, (N + 63) / 64);
    // layer 1: h1 = x @ W1 ; agg -> bufB
    gemm_kernel<false, false><<<g1, 256, 0, stream>>>(x, W1, nullptr, bufA, N, F_IN, H);
    gather_kernel<<<(N + 3) / 4, 256, 0, stream>>>(bufA, dinv, b1, off, esrc, enrm, bufB, N);

    // layer 2: h2 = relu(agg1) @ W2 ; agg -> bufB
    gemm_kernel<true, false><<<g1, 256, 0, stream>>>(bufB, W2, nullptr, bufA, N, H, H);
    gather_kernel<<<(N + 3) / 4, 256, 0, stream>>>(bufA, dinv, b2, off, esrc, enrm, bufB, N);

    // classifier: out = relu(agg2) @ Wc + bc
    dim3 g3((C + 63) / 64, (N + 63) / 64);
    gemm_kernel<true, true><<<g3, 256, 0, stream>>>(bufB, Wc, bc, out, N, H, C);
}

// Round 3
// 270.594 us; speedup vs baseline: 8.4644x; 1.8514x over previous
//
#include <hip/hip_runtime.h>
#include <math.h>

using short8 = __attribute__((ext_vector_type(8))) short;
using short4v = __attribute__((ext_vector_type(4))) short;
using f32x4 = __attribute__((ext_vector_type(4))) float;

__device__ inline short f2bf(float f) {
    unsigned u = __builtin_bit_cast(unsigned, f);
    unsigned r = (u + 0x7fffu + ((u >> 16) & 1u)) >> 16;
    return (short)r;
}
__device__ inline float bf2f(short s) {
    unsigned u = ((unsigned)(unsigned short)s) << 16;
    return __builtin_bit_cast(float, u);
}

// ---------------- CSR build ----------------

__global__ void zero_int_kernel(int* p, int n) {
    int i = blockIdx.x * blockDim.x + threadIdx.x;
    if (i < n) p[i] = 0;
}

__global__ void deg_count_kernel(const int* __restrict__ dst, int* deg, int e) {
    int i = blockIdx.x * blockDim.x + threadIdx.x;
    if (i < e) atomicAdd(&deg[dst[i]], 1);
}

__global__ void dinv_kernel(const int* __restrict__ deg, float* dinv, int n) {
    int i = blockIdx.x * blockDim.x + threadIdx.x;
    if (i < n) dinv[i] = rsqrtf((float)deg[i] + 1.0f);   // +1 self-loop
}

// 3-phase scan: partial (per-block inclusive), bsum exclusive scan, add
__global__ __launch_bounds__(1024) void scan_partial_kernel(
    const int* __restrict__ deg, int* __restrict__ off, int* __restrict__ bsum, int n)
{
    __shared__ int sdata[1024];
    int i = blockIdx.x * 1024 + threadIdx.x;
    int v = (i < n) ? deg[i] : 0;
    sdata[threadIdx.x] = v;
    __syncthreads();
    for (int s = 1; s < 1024; s <<= 1) {
        int t = (threadIdx.x >= s) ? sdata[threadIdx.x - s] : 0;
        __syncthreads();
        sdata[threadIdx.x] += t;
        __syncthreads();
    }
    if (i < n) off[i + 1] = sdata[threadIdx.x];
    if (threadIdx.x == 1023) bsum[blockIdx.x] = sdata[1023];
}

__global__ void scan_bsum_kernel(int* bsum, int nb) {   // one block, 64 threads
    int lane = threadIdx.x & 63;
    int orig = (lane < nb) ? bsum[lane] : 0;
    int v = orig;
    #pragma unroll
    for (int s = 1; s < 64; s <<= 1) {
        int t = __shfl_up(v, s, 64);
        if (lane >= s) v += t;
    }
    if (lane < nb) bsum[lane] = v - orig;   // exclusive
}

__global__ void scan_add_kernel(int* off, const int* __restrict__ bsum, int n) {
    int j = blockIdx.x * blockDim.x + threadIdx.x;
    if (j > n) return;
    if (j == 0) { off[0] = 0; return; }
    off[j] += bsum[(j - 1) >> 10];
}

__global__ void copy_int_kernel(const int* __restrict__ a, int* __restrict__ b, int n) {
    int i = blockIdx.x * blockDim.x + threadIdx.x;
    if (i < n) b[i] = a[i];
}

__global__ void fill_kernel(const int* __restrict__ src, const int* __restrict__ dst,
                            const float* __restrict__ dinv, int* __restrict__ cursor,
                            int* __restrict__ esrc, float* __restrict__ enrm, int e) {
    int i = blockIdx.x * blockDim.x + threadIdx.x;
    if (i < e) {
        int d = dst[i], s = src[i];
        int pos = atomicAdd(&cursor[d], 1);
        esrc[pos] = s;
        enrm[pos] = dinv[s] * dinv[d];
    }
}

// ---------------- dtype prep ----------------

__global__ void f32_to_bf16_kernel(const float* __restrict__ a, short* __restrict__ b, int n4) {
    int i = blockIdx.x * blockDim.x + threadIdx.x;   // n4 = n/4
    if (i >= n4) return;
    float4 v = ((const float4*)a)[i];
    short4v o;
    o.x = f2bf(v.x); o.y = f2bf(v.y); o.z = f2bf(v.z); o.w = f2bf(v.w);
    ((short4v*)b)[i] = o;
}

// Wt[n*K + k] = bf16(W[k*N + n])
__global__ void transpose_bf16_kernel(const float* __restrict__ W, short* __restrict__ Wt,
                                      int K, int N) {
    int idx = blockIdx.x * blockDim.x + threadIdx.x;
    if (idx >= K * N) return;
    int k = idx / N, n = idx % N;
    Wt[n * K + k] = f2bf(W[idx]);
}

// ---------------- bf16 MFMA GEMM: C = A[MxK] @ Wt[NCxK]^T ----------------
// block 256 thr = 4 waves; tile BM=128 BN=64 BK=32; wave computes 64x32
// via 4x2 of 16x16x32 MFMAs. LDS rows padded to 40 shorts (80B) -> max
// 2-way bank aliasing on ds_read_b128 (free).

template<bool FP32OUT>
__global__ __launch_bounds__(256) void mfma_gemm_kernel(
    const short* __restrict__ A, const short* __restrict__ Wt,
    const float* __restrict__ bias, void* __restrict__ Cout,
    int M, int K, int NC)
{
    __shared__ short As[128 * 40];
    __shared__ short Bs[64 * 40];

    const int tid = threadIdx.x;
    const int wave = tid >> 6, lane = tid & 63;
    const int m0 = blockIdx.y * 128, n0 = blockIdx.x * 64;
    const int wm = (wave >> 1) * 64, wn = (wave & 1) * 32;

    // staging: thread t loads rows (t>>2) and 64+(t>>2) of A, row (t>>2) of B,
    // 8 bf16 (16B) at k-slot (t&3)*8.
    const int sar = tid >> 2;
    const int sak = (tid & 3) * 8;
    int ga0 = m0 + sar;      if (ga0 >= M) ga0 = M - 1;
    int ga1 = m0 + 64 + sar; if (ga1 >= M) ga1 = M - 1;
    int gb  = n0 + sar;      if (gb >= NC) gb = NC - 1;
    const short* pa0 = A + (size_t)ga0 * K + sak;
    const short* pa1 = A + (size_t)ga1 * K + sak;
    const short* pb  = Wt + (size_t)gb * K + sak;

    const int lw0 = sar * 40 + (tid & 3) * 8;          // As slot row sar
    const int lw1 = (64 + sar) * 40 + (tid & 3) * 8;   // As slot row 64+sar

    f32x4 acc[4][2] = {};

    const int fr = lane & 15;         // frag row/col within 16
    const int fk = (lane >> 4) * 8;   // k offset of this lane's 8 elements

    for (int k0 = 0; k0 < K; k0 += 32) {
        short8 va0 = *(const short8*)(pa0 + k0);
        short8 va1 = *(const short8*)(pa1 + k0);
        short8 vb  = *(const short8*)(pb + k0);
        __syncthreads();
        *(short8*)&As[lw0] = va0;
        *(short8*)&As[lw1] = va1;
        *(short8*)&Bs[lw0] = vb;
        __syncthreads();

        short8 af[4], bfr[2];
        #pragma unroll
        for (int mt = 0; mt < 4; ++mt)
            af[mt] = *(const short8*)&As[(wm + mt * 16 + fr) * 40 + fk];
        #pragma unroll
        for (int nt = 0; nt < 2; ++nt)
            bfr[nt] = *(const short8*)&Bs[(wn + nt * 16 + fr) * 40 + fk];

        #pragma unroll
        for (int mt = 0; mt < 4; ++mt)
            #pragma unroll
            for (int nt = 0; nt < 2; ++nt)
                acc[mt][nt] = __builtin_amdgcn_mfma_f32_16x16x32_bf16(
                    af[mt], bfr[nt], acc[mt][nt], 0, 0, 0);
    }

    // epilogue: D mapping col = lane&15, row = (lane>>4)*4 + reg
    #pragma unroll
    for (int mt = 0; mt < 4; ++mt) {
        #pragma unroll
        for (int nt = 0; nt < 2; ++nt) {
            #pragma unroll
            for (int r = 0; r < 4; ++r) {
                int grow = m0 + wm + mt * 16 + (lane >> 4) * 4 + r;
                int gcol = n0 + wn + nt * 16 + (lane & 15);
                if (grow < M && gcol < NC) {
                    float v = acc[mt][nt][r];
                    if (FP32OUT)
                        ((float*)Cout)[(size_t)grow * NC + gcol] = v + bias[gcol];
                    else
                        ((short*)Cout)[(size_t)grow * NC + gcol] = f2bf(v);
                }
            }
        }
    }
}

// ---------------- CSR gather (bf16 in/out, fp32 acc, fused bias+ReLU) ----------------
// one wave per node, lane covers 4 of 256 features (8B loads).

__global__ __launch_bounds__(256) void gather_kernel(
    const short* __restrict__ h, const float* __restrict__ dinv,
    const float* __restrict__ bias, const int* __restrict__ off,
    const int* __restrict__ esrc, const float* __restrict__ enrm,
    short* __restrict__ out, int n)
{
    int node = blockIdx.x * 4 + (threadIdx.x >> 6);
    if (node >= n) return;
    int lane = threadIdx.x & 63;
    int f = lane * 4;

    float di = dinv[node];
    float w = di * di;
    short4v hv = *(const short4v*)(h + (size_t)node * 256 + f);
    float a0 = bf2f(hv.x) * w + bias[f + 0];
    float a1 = bf2f(hv.y) * w + bias[f + 1];
    float a2 = bf2f(hv.z) * w + bias[f + 2];
    float a3 = bf2f(hv.w) * w + bias[f + 3];

    int e0 = off[node], e1 = off[node + 1];
    for (int e = e0; e < e1; ++e) {
        int s = esrc[e];
        float wn = enrm[e];
        short4v v = *(const short4v*)(h + (size_t)s * 256 + f);
        a0 = fmaf(bf2f(v.x), wn, a0);
        a1 = fmaf(bf2f(v.y), wn, a1);
        a2 = fmaf(bf2f(v.z), wn, a2);
        a3 = fmaf(bf2f(v.w), wn, a3);
    }
    short4v o;
    o.x = f2bf(fmaxf(a0, 0.f));
    o.y = f2bf(fmaxf(a1, 0.f));
    o.z = f2bf(fmaxf(a2, 0.f));
    o.w = f2bf(fmaxf(a3, 0.f));
    *(short4v*)(out + (size_t)node * 256 + f) = o;
}

// ---------------- launch ----------------

extern "C" void kernel_launch(void* const* d_in, const int* in_sizes, int n_in,
                              void* d_out, int out_size, void* d_ws, size_t ws_size,
                              hipStream_t stream) {
    const float* x  = (const float*)d_in[0];
    const int*   ei = (const int*)d_in[1];
    const float* W1 = (const float*)d_in[2];
    const float* b1 = (const float*)d_in[3];
    const float* W2 = (const float*)d_in[4];
    const float* b2 = (const float*)d_in[5];
    const float* Wc = (const float*)d_in[6];
    const float* bc = (const float*)d_in[7];
    float* out = (float*)d_out;

    const int E = in_sizes[1] / 2;
    const int N = in_sizes[0] / 128;
    const int F_IN = 128, H = 256, C = 32;
    const int* src = ei;
    const int* dst = ei + E;

    // workspace layout (shorts first, all 16B-aligned)
    short* hA  = (short*)d_ws;                      // N*256
    short* hB  = hA + (size_t)N * 256;              // N*256
    short* xb  = hB + (size_t)N * 256;              // N*128
    short* Wt1 = xb + (size_t)N * 128;              // 256*128
    short* Wt2 = Wt1 + 256 * 128;                   // 256*256
    short* Wtc = Wt2 + 256 * 256;                   // 32*256
    float* dinv = (float*)(Wtc + 32 * 256);         // N
    float* enrm = dinv + N;                         // E
    int*   deg  = (int*)(enrm + E);                 // N
    int*   off  = deg + N;                          // N+1
    int*   cur  = off + N + 1;                      // N
    int*   esrc = cur + N;                          // E
    int*   bsum = esrc + E;                         // 64

    const int TB = 256;
    const int nb = (N + 1023) / 1024;

    // CSR build
    zero_int_kernel   <<<(N + TB - 1) / TB, TB, 0, stream>>>(deg, N);
    deg_count_kernel  <<<(E + TB - 1) / TB, TB, 0, stream>>>(dst, deg, E);
    dinv_kernel       <<<(N + TB - 1) / TB, TB, 0, stream>>>(deg, dinv, N);
    scan_partial_kernel<<<nb, 1024, 0, stream>>>(deg, off, bsum, N);
    scan_bsum_kernel  <<<1, 64, 0, stream>>>(bsum, nb);
    scan_add_kernel   <<<(N + 1 + TB) / TB, TB, 0, stream>>>(off, bsum, N);
    copy_int_kernel   <<<(N + TB - 1) / TB, TB, 0, stream>>>(off, cur, N);
    fill_kernel       <<<(E + TB - 1) / TB, TB, 0, stream>>>(src, dst, dinv, cur, esrc, enrm, E);

    // dtype prep
    f32_to_bf16_kernel<<<((N * F_IN / 4) + TB - 1) / TB, TB, 0, stream>>>(x, xb, N * F_IN / 4);
    transpose_bf16_kernel<<<(F_IN * H + TB - 1) / TB, TB, 0, stream>>>(W1, Wt1, F_IN, H);
    transpose_bf16_kernel<<<(H * H + TB - 1) / TB, TB, 0, stream>>>(W2, Wt2, H, H);
    transpose_bf16_kernel<<<(H * C + TB - 1) / TB, TB, 0, stream>>>(Wc, Wtc, H, C);

    const int gy = (N + 127) / 128;
    // layer 1: hA = xb @ W1 ; gather -> hB (bias+relu)
    mfma_gemm_kernel<false><<<dim3(H / 64, gy), 256, 0, stream>>>(xb, Wt1, nullptr, hA, N, F_IN, H);
    gather_kernel<<<(N + 3) / 4, 256, 0, stream>>>(hA, dinv, b1, off, esrc, enrm, hB, N);

    // layer 2: hA = hB @ W2 ; gather -> hB
    mfma_gemm_kernel<false><<<dim3(H / 64, gy), 256, 0, stream>>>(hB, Wt2, nullptr, hA, N, H, H);
    gather_kernel<<<(N + 3) / 4, 256, 0, stream>>>(hA, dinv, b2, off, esrc, enrm, hB, N);

    // classifier: out = hB @ Wc + bc (fp32 out)
    mfma_gemm_kernel<true><<<dim3(1, gy), 256, 0, stream>>>(hB, Wtc, bc, out, N, H, C);
}

// Round 4
// 241.044 us; speedup vs baseline: 9.5020x; 1.1226x over previous
//
#include <hip/hip_runtime.h>
#include <math.h>

using short8 = __attribute__((ext_vector_type(8))) short;
using short4v = __attribute__((ext_vector_type(4))) short;
using f32x4 = __attribute__((ext_vector_type(4))) float;

__device__ inline short f2bf(float f) {
    unsigned u = __builtin_bit_cast(unsigned, f);
    unsigned r = (u + 0x7fffu + ((u >> 16) & 1u)) >> 16;
    return (short)r;
}
__device__ inline float bf2f(short s) {
    unsigned u = ((unsigned)(unsigned short)s) << 16;
    return __builtin_bit_cast(float, u);
}

// ---------------- CSR build ----------------

__global__ void zero_int_kernel(int* p, int n) {
    int i = blockIdx.x * blockDim.x + threadIdx.x;
    if (i < n) p[i] = 0;
}

__global__ void deg_count_kernel(const int* __restrict__ dst, int* deg, int e) {
    int i = blockIdx.x * blockDim.x + threadIdx.x;
    if (i < e) atomicAdd(&deg[dst[i]], 1);
}

// per-block inclusive scan of deg -> off[i+1]; also dinv = rsqrt(deg+1)
__global__ __launch_bounds__(1024) void scan_partial_kernel(
    const int* __restrict__ deg, int* __restrict__ off, int* __restrict__ bsum,
    float* __restrict__ dinv, int n)
{
    __shared__ int sdata[1024];
    int i = blockIdx.x * 1024 + threadIdx.x;
    int v = (i < n) ? deg[i] : 0;
    if (i < n) dinv[i] = rsqrtf((float)v + 1.0f);   // +1 self-loop
    sdata[threadIdx.x] = v;
    __syncthreads();
    for (int s = 1; s < 1024; s <<= 1) {
        int t = (threadIdx.x >= s) ? sdata[threadIdx.x - s] : 0;
        __syncthreads();
        sdata[threadIdx.x] += t;
        __syncthreads();
    }
    if (i < n) off[i + 1] = sdata[threadIdx.x];
    if (threadIdx.x == 1023) bsum[blockIdx.x] = sdata[1023];
}

__global__ void scan_bsum_kernel(int* bsum, int nb) {   // one wave
    int lane = threadIdx.x & 63;
    int orig = (lane < nb) ? bsum[lane] : 0;
    int v = orig;
    #pragma unroll
    for (int s = 1; s < 64; s <<= 1) {
        int t = __shfl_up(v, s, 64);
        if (lane >= s) v += t;
    }
    if (lane < nb) bsum[lane] = v - orig;   // exclusive
}

// finalize off (+ block prefix) and init cursor
__global__ void scan_add_kernel(int* off, int* cur, const int* __restrict__ bsum, int n) {
    int j = blockIdx.x * blockDim.x + threadIdx.x;
    if (j > n) return;
    int v = (j == 0) ? 0 : off[j] + bsum[(j - 1) >> 10];
    off[j] = v;
    if (j < n) cur[j] = v;
}

__global__ void fill_kernel(const int* __restrict__ src, const int* __restrict__ dst,
                            const float* __restrict__ dinv, int* __restrict__ cursor,
                            int* __restrict__ esrc, float* __restrict__ enrm, int e) {
    int i = blockIdx.x * blockDim.x + threadIdx.x;
    if (i < e) {
        int d = dst[i], s = src[i];
        int pos = atomicAdd(&cursor[d], 1);
        esrc[pos] = s;
        enrm[pos] = dinv[s] * dinv[d];
    }
}

// ---------------- dtype prep ----------------

__global__ void f32_to_bf16_kernel(const float* __restrict__ a, short* __restrict__ b, int n4) {
    int i = blockIdx.x * blockDim.x + threadIdx.x;
    if (i >= n4) return;
    float4 v = ((const float4*)a)[i];
    short4v o;
    o.x = f2bf(v.x); o.y = f2bf(v.y); o.z = f2bf(v.z); o.w = f2bf(v.w);
    ((short4v*)b)[i] = o;
}

// all three weight transposes in one kernel: Wt[n*K+k] = bf16(W[k*N+n])
__global__ void wprep_kernel(const float* __restrict__ W1, const float* __restrict__ W2,
                             const float* __restrict__ Wc, short* __restrict__ Wt1,
                             short* __restrict__ Wt2, short* __restrict__ Wtc) {
    int idx = blockIdx.x * blockDim.x + threadIdx.x;
    if (idx < 128 * 256) {                     // W1: K=128, N=256
        int k = idx >> 8, n = idx & 255;
        Wt1[n * 128 + k] = f2bf(W1[idx]);
        return;
    }
    idx -= 128 * 256;
    if (idx < 256 * 256) {                     // W2: K=256, N=256
        int k = idx >> 8, n = idx & 255;
        Wt2[n * 256 + k] = f2bf(W2[idx]);
        return;
    }
    idx -= 256 * 256;
    if (idx < 256 * 32) {                      // Wc: K=256, N=32
        int k = idx >> 5, n = idx & 31;
        Wtc[n * 256 + k] = f2bf(Wc[idx]);
    }
}

// ---------------- bf16 MFMA GEMM: C = A[MxK] @ Wt[NCxK]^T + bias (, relu) ----------------
// block 256 thr = 4 waves; tile BM=128 BN=64 BK=32; wave computes 64x32.

template<bool RELU_BF16OUT>
__global__ __launch_bounds__(256) void mfma_gemm_kernel(
    const short* __restrict__ A, const short* __restrict__ Wt,
    const float* __restrict__ bias, void* __restrict__ Cout,
    int M, int K, int NC)
{
    __shared__ short As[128 * 40];
    __shared__ short Bs[64 * 40];

    const int tid = threadIdx.x;
    const int wave = tid >> 6, lane = tid & 63;
    const int m0 = blockIdx.y * 128, n0 = blockIdx.x * 64;
    const int wm = (wave >> 1) * 64, wn = (wave & 1) * 32;

    const int sar = tid >> 2;
    const int sak = (tid & 3) * 8;
    int ga0 = m0 + sar;      if (ga0 >= M) ga0 = M - 1;
    int ga1 = m0 + 64 + sar; if (ga1 >= M) ga1 = M - 1;
    int gb  = n0 + sar;      if (gb >= NC) gb = NC - 1;
    const short* pa0 = A + (size_t)ga0 * K + sak;
    const short* pa1 = A + (size_t)ga1 * K + sak;
    const short* pb  = Wt + (size_t)gb * K + sak;

    const int lw0 = sar * 40 + (tid & 3) * 8;
    const int lw1 = (64 + sar) * 40 + (tid & 3) * 8;

    f32x4 acc[4][2] = {};

    const int fr = lane & 15;
    const int fk = (lane >> 4) * 8;

    for (int k0 = 0; k0 < K; k0 += 32) {
        short8 va0 = *(const short8*)(pa0 + k0);
        short8 va1 = *(const short8*)(pa1 + k0);
        short8 vb  = *(const short8*)(pb + k0);
        __syncthreads();
        *(short8*)&As[lw0] = va0;
        *(short8*)&As[lw1] = va1;
        *(short8*)&Bs[lw0] = vb;
        __syncthreads();

        short8 af[4], bfr[2];
        #pragma unroll
        for (int mt = 0; mt < 4; ++mt)
            af[mt] = *(const short8*)&As[(wm + mt * 16 + fr) * 40 + fk];
        #pragma unroll
        for (int nt = 0; nt < 2; ++nt)
            bfr[nt] = *(const short8*)&Bs[(wn + nt * 16 + fr) * 40 + fk];

        #pragma unroll
        for (int mt = 0; mt < 4; ++mt)
            #pragma unroll
            for (int nt = 0; nt < 2; ++nt)
                acc[mt][nt] = __builtin_amdgcn_mfma_f32_16x16x32_bf16(
                    af[mt], bfr[nt], acc[mt][nt], 0, 0, 0);
    }

    // epilogue: D mapping col = lane&15, row = (lane>>4)*4 + reg
    #pragma unroll
    for (int mt = 0; mt < 4; ++mt) {
        #pragma unroll
        for (int nt = 0; nt < 2; ++nt) {
            #pragma unroll
            for (int r = 0; r < 4; ++r) {
                int grow = m0 + wm + mt * 16 + (lane >> 4) * 4 + r;
                int gcol = n0 + wn + nt * 16 + (lane & 15);
                if (grow < M && gcol < NC) {
                    float v = acc[mt][nt][r] + bias[gcol];
                    if (RELU_BF16OUT)
                        ((short*)Cout)[(size_t)grow * NC + gcol] = f2bf(fmaxf(v, 0.f));
                    else
                        ((float*)Cout)[(size_t)grow * NC + gcol] = v;
                }
            }
        }
    }
}

// ---------------- CSR gather: out[n] = h[n]*dinv[n]^2 + sum_e h[src]*nrm ----------------
// LPN lanes per node (F = LPN*4 features); 4-way edge unroll for MLP.

template<int LPN>
__global__ __launch_bounds__(256) void gather_kernel(
    const short* __restrict__ h, const float* __restrict__ dinv,
    const int* __restrict__ off, const int* __restrict__ esrc,
    const float* __restrict__ enrm, short* __restrict__ out, int n)
{
    const int F = LPN * 4;
    int node = (blockIdx.x * 256 + threadIdx.x) / LPN;
    if (node >= n) return;
    int lane = threadIdx.x % LPN;
    int f = lane * 4;

    float di = dinv[node];
    float w = di * di;
    const size_t rb = (size_t)node * F + f;
    short4v hv = *(const short4v*)(h + rb);
    float a0 = bf2f(hv.x) * w;
    float a1 = bf2f(hv.y) * w;
    float a2 = bf2f(hv.z) * w;
    float a3 = bf2f(hv.w) * w;

    int e = off[node], e1 = off[node + 1];
    for (; e + 4 <= e1; e += 4) {
        int s0 = esrc[e + 0], s1 = esrc[e + 1], s2 = esrc[e + 2], s3 = esrc[e + 3];
        float w0 = enrm[e + 0], w1 = enrm[e + 1], w2 = enrm[e + 2], w3 = enrm[e + 3];
        short4v v0 = *(const short4v*)(h + (size_t)s0 * F + f);
        short4v v1 = *(const short4v*)(h + (size_t)s1 * F + f);
        short4v v2 = *(const short4v*)(h + (size_t)s2 * F + f);
        short4v v3 = *(const short4v*)(h + (size_t)s3 * F + f);
        a0 = fmaf(bf2f(v0.x), w0, a0); a1 = fmaf(bf2f(v0.y), w0, a1);
        a2 = fmaf(bf2f(v0.z), w0, a2); a3 = fmaf(bf2f(v0.w), w0, a3);
        a0 = fmaf(bf2f(v1.x), w1, a0); a1 = fmaf(bf2f(v1.y), w1, a1);
        a2 = fmaf(bf2f(v1.z), w1, a2); a3 = fmaf(bf2f(v1.w), w1, a3);
        a0 = fmaf(bf2f(v2.x), w2, a0); a1 = fmaf(bf2f(v2.y), w2, a1);
        a2 = fmaf(bf2f(v2.z), w2, a2); a3 = fmaf(bf2f(v2.w), w2, a3);
        a0 = fmaf(bf2f(v3.x), w3, a0); a1 = fmaf(bf2f(v3.y), w3, a1);
        a2 = fmaf(bf2f(v3.z), w3, a2); a3 = fmaf(bf2f(v3.w), w3, a3);
    }
    for (; e < e1; ++e) {
        int s = esrc[e];
        float wn = enrm[e];
        short4v v = *(const short4v*)(h + (size_t)s * F + f);
        a0 = fmaf(bf2f(v.x), wn, a0);
        a1 = fmaf(bf2f(v.y), wn, a1);
        a2 = fmaf(bf2f(v.z), wn, a2);
        a3 = fmaf(bf2f(v.w), wn, a3);
    }
    short4v o;
    o.x = f2bf(a0); o.y = f2bf(a1); o.z = f2bf(a2); o.w = f2bf(a3);
    *(short4v*)(out + rb) = o;
}

// ---------------- launch ----------------

extern "C" void kernel_launch(void* const* d_in, const int* in_sizes, int n_in,
                              void* d_out, int out_size, void* d_ws, size_t ws_size,
                              hipStream_t stream) {
    const float* x  = (const float*)d_in[0];
    const int*   ei = (const int*)d_in[1];
    const float* W1 = (const float*)d_in[2];
    const float* b1 = (const float*)d_in[3];
    const float* W2 = (const float*)d_in[4];
    const float* b2 = (const float*)d_in[5];
    const float* Wc = (const float*)d_in[6];
    const float* bc = (const float*)d_in[7];
    float* out = (float*)d_out;

    const int E = in_sizes[1] / 2;
    const int N = in_sizes[0] / 128;
    const int F_IN = 128, H = 256, C = 32;
    const int* src = ei;
    const int* dst = ei + E;

    // workspace layout (shorts first, 16B aligned)
    short* xb   = (short*)d_ws;                     // N*128  bf16 X
    short* aggX = xb + (size_t)N * 128;             // N*128  A_hat @ X
    short* hA   = aggX + (size_t)N * 128;           // N*256
    short* hB   = hA + (size_t)N * 256;             // N*256
    short* Wt1  = hB + (size_t)N * 256;             // 256*128
    short* Wt2  = Wt1 + 256 * 128;                  // 256*256
    short* Wtc  = Wt2 + 256 * 256;                  // 32*256
    float* dinv = (float*)(Wtc + 32 * 256);         // N
    float* enrm = dinv + N;                         // E
    int*   deg  = (int*)(enrm + E);                 // N
    int*   off  = deg + N;                          // N+1
    int*   cur  = off + N + 1;                      // N
    int*   esrc = cur + N;                          // E
    int*   bsum = esrc + E;                         // 64

    const int TB = 256;
    const int nb = (N + 1023) / 1024;

    // prep (independent of CSR)
    f32_to_bf16_kernel<<<((N * F_IN / 4) + TB - 1) / TB, TB, 0, stream>>>(x, xb, N * F_IN / 4);
    wprep_kernel<<<(128 * 256 + 256 * 256 + 256 * 32 + TB - 1) / TB, TB, 0, stream>>>(
        W1, W2, Wc, Wt1, Wt2, Wtc);

    // CSR build
    zero_int_kernel    <<<(N + TB - 1) / TB, TB, 0, stream>>>(deg, N);
    deg_count_kernel   <<<(E + TB - 1) / TB, TB, 0, stream>>>(dst, deg, E);
    scan_partial_kernel<<<nb, 1024, 0, stream>>>(deg, off, bsum, dinv, N);
    scan_bsum_kernel   <<<1, 64, 0, stream>>>(bsum, nb);
    scan_add_kernel    <<<(N + 1 + TB) / TB, TB, 0, stream>>>(off, cur, bsum, N);
    fill_kernel        <<<(E + TB - 1) / TB, TB, 0, stream>>>(src, dst, dinv, cur, esrc, enrm, E);

    const int gy = (N + 127) / 128;
    // layer 1: aggX = A_hat @ X ; hA = relu(aggX @ W1 + b1)
    gather_kernel<32><<<((size_t)N * 32 + TB - 1) / TB, TB, 0, stream>>>(
        xb, dinv, off, esrc, enrm, aggX, N);
    mfma_gemm_kernel<true><<<dim3(H / 64, gy), 256, 0, stream>>>(aggX, Wt1, b1, hA, N, F_IN, H);

    // layer 2: hB = A_hat @ hA ; hA = relu(hB @ W2 + b2)
    gather_kernel<64><<<((size_t)N * 64 + TB - 1) / TB, TB, 0, stream>>>(
        hA, dinv, off, esrc, enrm, hB, N);
    mfma_gemm_kernel<true><<<dim3(H / 64, gy), 256, 0, stream>>>(hB, Wt2, b2, hA, N, H, H);

    // classifier: out = hA @ Wc + bc (fp32)
    mfma_gemm_kernel<false><<<dim3(1, gy), 256, 0, stream>>>(hA, Wtc, bc, out, N, H, C);
}